// Round 1
// baseline (90.262 us; speedup 1.0000x reference)
//
#include <hip/hip_runtime.h>
#include <math.h>

// Problem constants (fixed by reference setup_inputs)
#define NN 32768
#define LL 256
#define CC 64
#define EPSV 1e-12f

// ---------------- Kernel 1: row softmax of leaf_scores -> Q in workspace ----
// One wave (64 lanes) per row l; C == 64 so lane k handles one element.
__global__ __launch_bounds__(64) void softmax_rows_kernel(
    const float* __restrict__ scores, float* __restrict__ Q) {
    const int l = blockIdx.x;
    const int k = threadIdx.x;
    float v = scores[l * CC + k];
    // wave-wide max (64 lanes)
    float m = v;
    #pragma unroll
    for (int off = 32; off > 0; off >>= 1) m = fmaxf(m, __shfl_xor(m, off));
    float e = expf(v - m);
    float s = e;
    #pragma unroll
    for (int off = 32; off > 0; off >>= 1) s += __shfl_xor(s, off);
    Q[l * CC + k] = e / s;
}

// ---------------- Kernel 2: out = log( clamp(mu) @ Q ) ---------------------
// Block tile: 64 rows (n) x 64 cols (k == all of C), K-chunked by 64.
// 256 threads: tx = tid&15 -> 4 cols each, ty = tid>>4 -> 4 rows each.
// LDS: muS[64][68], QS[64][68]  (pad 4 floats keeps 16B alignment, breaks
// power-of-2 strides down to 2-way conflicts which are free).
#define BM 64
#define BK 64
#define LDW (BK + 4)   // 68 floats per LDS row

__global__ __launch_bounds__(256) void leaf_mix_kernel(
    const float* __restrict__ mu, const float* __restrict__ Q,
    float* __restrict__ out) {
    __shared__ float muS[BM * LDW];
    __shared__ float QS[BK * LDW];

    const int tid = threadIdx.x;
    const int tx = tid & 15;      // col group: cols tx*4 .. tx*4+3
    const int ty = tid >> 4;      // row group: rows ty*4 .. ty*4+3
    const int rowBase = blockIdx.x * BM;

    __align__(16) float acc[4][4] = {{0.f,0.f,0.f,0.f},{0.f,0.f,0.f,0.f},
                                     {0.f,0.f,0.f,0.f},{0.f,0.f,0.f,0.f}};

    for (int kb = 0; kb < LL; kb += BK) {
        // ---- stage mu tile (64 rows x 64 l), clamped, row-major in LDS ----
        #pragma unroll
        for (int j = 0; j < 4; ++j) {
            const int f = tid + 256 * j;        // float4 index 0..1023
            const int r = f >> 4;               // 16 float4 per row
            const int c = f & 15;
            float4 v = *(const float4*)(mu + (size_t)(rowBase + r) * LL + kb + c * 4);
            v.x = fmaxf(v.x, EPSV); v.y = fmaxf(v.y, EPSV);
            v.z = fmaxf(v.z, EPSV); v.w = fmaxf(v.w, EPSV);
            *(float4*)(muS + r * LDW + c * 4) = v;
        }
        // ---- stage Q tile (64 l x 64 k), row-major in LDS ----
        #pragma unroll
        for (int j = 0; j < 4; ++j) {
            const int f = tid + 256 * j;
            const int r = f >> 4;
            const int c = f & 15;
            *(float4*)(QS + r * LDW + c * 4) =
                *(const float4*)(Q + (size_t)(kb + r) * CC + c * 4);
        }
        __syncthreads();

        // ---- inner product: 4x4 register tile, l unrolled by 4 ----
        #pragma unroll
        for (int l = 0; l < BK; l += 4) {
            __align__(16) float qv[4][4];
            __align__(16) float mv[4][4];
            #pragma unroll
            for (int j = 0; j < 4; ++j)
                *(float4*)qv[j] = *(const float4*)(QS + (l + j) * LDW + tx * 4);
            #pragma unroll
            for (int i = 0; i < 4; ++i)
                *(float4*)mv[i] = *(const float4*)(muS + (ty * 4 + i) * LDW + l);
            #pragma unroll
            for (int i = 0; i < 4; ++i)
                #pragma unroll
                for (int j = 0; j < 4; ++j)
                    #pragma unroll
                    for (int c = 0; c < 4; ++c)
                        acc[i][c] += mv[i][j] * qv[j][c];
        }
        __syncthreads();
    }

    // ---- epilogue: log + coalesced float4 store ----
    #pragma unroll
    for (int i = 0; i < 4; ++i) {
        float4 o;
        o.x = logf(acc[i][0]);
        o.y = logf(acc[i][1]);
        o.z = logf(acc[i][2]);
        o.w = logf(acc[i][3]);
        *(float4*)(out + (size_t)(rowBase + ty * 4 + i) * CC + tx * 4) = o;
    }
}

extern "C" void kernel_launch(void* const* d_in, const int* in_sizes, int n_in,
                              void* d_out, int out_size, void* d_ws, size_t ws_size,
                              hipStream_t stream) {
    const float* mu     = (const float*)d_in[0];   // (32768, 256) f32
    const float* scores = (const float*)d_in[1];   // (256, 64)   f32
    float* out = (float*)d_out;                    // (32768, 64) f32
    float* Q   = (float*)d_ws;                     // 256*64 f32 = 64 KB scratch

    softmax_rows_kernel<<<LL, 64, 0, stream>>>(scores, Q);
    leaf_mix_kernel<<<NN / BM, 256, 0, stream>>>(mu, Q, out);
}